// Round 11
// baseline (128.169 us; speedup 1.0000x reference)
//
#include <hip/hip_runtime.h>
#include <hip/hip_fp16.h>

// Problem constants (B=4, C=128, H=W=64 -> HW=4096)
#define BATCH 4
#define CCH   128
#define HWSZ  4096

typedef _Float16 half8 __attribute__((ext_vector_type(8)));
typedef short short8 __attribute__((ext_vector_type(8)));
typedef unsigned short ushort8 __attribute__((ext_vector_type(8)));
typedef float floatx4 __attribute__((ext_vector_type(4)));
typedef unsigned int uint2v __attribute__((ext_vector_type(2)));

__device__ __forceinline__ unsigned short f2bf(float f) {
    union { float f; unsigned u; } v; v.f = f;
    return (unsigned short)((v.u + 0x7fffu + ((v.u >> 16) & 1u)) >> 16);
}

// pack 2 f32 -> 2 bf16 in one dword (low = a, high = b)
__device__ __forceinline__ unsigned cvtpk(float a, float b) {
    unsigned r;
    asm("v_cvt_pk_bf16_f32 %0, %1, %2" : "=v"(r) : "v"(a), "v"(b));
    return r;
}

// async global->LDS, 16B per lane; LDS dest = per-lane base+lane*16 linear.
#define GLDS(gsrc, ldst) __builtin_amdgcn_global_load_lds( \
    (const __attribute__((address_space(1))) void*)(gsrc), \
    (__attribute__((address_space(3))) void*)(ldst), 16, 0, 0)

// single per-chunk barrier: drain own LDS reads/writes + own GLDS DMAs,
// then rendezvous. sched fences pin the segment contents.
#define FBARV() do { __builtin_amdgcn_sched_barrier(0); \
    asm volatile("s_waitcnt vmcnt(0) lgkmcnt(0)" ::: "memory"); \
    __builtin_amdgcn_s_barrier(); \
    __builtin_amdgcn_sched_barrier(0); } while (0)

// prep: x fp32 [B][C][HW] ->
//   xt  fp16 [B][HW][C]  (transposed, for gram A staging)
//   xft bf16 MFMA-A-fragment-tiled: per batch, unit u = (t*8+ct)*2+kf holds
//     512 ushorts: lane (l16=c&15, lg)*8 + j  = A[c][k=lg*8+j] of chunk t,
//     c-tile ct, k-half kf. Fused paf load = base + lane*16B (coalesced b128).
__global__ __launch_bounds__(256) void prep_kernel(
    const float* __restrict__ x1, const float* __restrict__ x2,
    _Float16* __restrict__ x1t, _Float16* __restrict__ x2t,
    unsigned short* __restrict__ x1ft, unsigned short* __restrict__ x2ft)
{
    __shared__ float lds[32][33];
    int idx = blockIdx.x;            // 0..4095
    int which = idx >> 11;           // 0: x1, 1: x2
    int r = idx & 2047;
    int cb  = r & 3;                 // C/32  = 4
    int hwb = (r >> 2) & 127;        // HW/32 = 128
    int b   = r >> 9;                // 4 batches
    const float* x = which ? x2 : x1;
    _Float16* xt = which ? x2t : x1t;
    unsigned short* xft = which ? x2ft : x1ft;
    int tid = threadIdx.x;
    int tc = tid >> 5, th = tid & 31;
    #pragma unroll
    for (int k = 0; k < 4; ++k) {
        int cl = tc + 8 * k;
        lds[cl][th] = x[((size_t)b * CCH + cb * 32 + cl) * HWSZ + hwb * 32 + th];
    }
    __syncthreads();
    // xt transpose store
    #pragma unroll
    for (int k = 0; k < 4; ++k) {
        int hl = tc + 8 * k;
        xt[((size_t)b * HWSZ + hwb * 32 + hl) * CCH + cb * 32 + th] =
            (_Float16)lds[th][hl];
    }
    // xft tiled store: 128 units of 16B (32 c x 4 segs)
    if (tid < 128) {
        int c_local = tid >> 2, seg = tid & 3;
        int c = cb * 32 + c_local;
        int ct = c >> 4, l16c = c & 15;
        int t = hwb >> 1, kf = hwb & 1;
        ushort8 v;
        #pragma unroll
        for (int j = 0; j < 8; ++j) v[j] = f2bf(lds[c_local][seg * 8 + j]);
        size_t ui = ((((size_t)t * 8 + ct) * 2 + kf) * 64 + seg * 16 + l16c) * 8;
        *(ushort8*)&xft[(size_t)b * 524288 + ui] = v;
    }
}

// Fused partial pass (BOTH softmax passes in one launch), col-tile = 128,
// 16 waves. R10 body, software-pipelined to ONE barrier per chunk:
// AF[2] + EB[2] double-buffered (64KB LDS, 2 blocks/CU). Segment between
// barriers: {issue paf(t-1), GLDS AF(t+1)} || gram(t) || exp(t)+EBwrite ||
// PV(t-1). Gram and PV MFMAs are independent -> scheduler interleaves,
// hiding ebf latency under gram and exp under PV.
// Race-proof: each buffer's readers drain (FBARV lgkm/vmcnt) before
// signaling barrier t; its next writer writes only after barrier t.
//   A[row,col] = sum_c loopT[row][c]*blockT[col][c]   (fp16 MFMA, K=128)
//   E = exp(A) (bf16 -> swizzled LDS)
//   accP[c][col] += sum_row loopF[c][row]*E[row][col] (bf16 MFMA)
//   colsum[col]  += sum_row E
__global__ __launch_bounds__(1024, 4) void fused_part(
    const _Float16* __restrict__ x1t, const _Float16* __restrict__ x2t,
    const unsigned short* __restrict__ x1ft, const unsigned short* __restrict__ x2ft,
    float* __restrict__ accP1, float* __restrict__ cs1,
    float* __restrict__ accP2, float* __restrict__ cs2,
    int P, int passSel)
{
    __shared__ unsigned short AF[2][8192];   // 64 rows x 128 c fp16, swizzled
    __shared__ unsigned short EB[2][8192];   // 128 cols x 64 rows bf16, swizzled

    int bid = blockIdx.x;
    int pass, bidp;
    if (passSel < 0) { pass = bid >> 8; bidp = bid & 255; }
    else             { pass = passSel;  bidp = bid; }
    int xcd = bidp & 7, grp = bidp >> 3;  // grp 0..16P-1
    int b = xcd >> 1;                     // 2 XCDs per batch (L2 locality)
    int slice = (grp & 15) + 16 * (xcd & 1);   // 0..31 (128 cols each)
    int part = grp >> 4;                  // 0..P-1
    int tid = threadIdx.x;
    int wave = tid >> 6, lane = tid & 63;
    int l16 = lane & 15, lg = lane >> 4;
    int nt = wave & 3, mh = wave >> 2;    // gram: row-tile nt, col-32-group mh
    int swz = l16 & 7;
    int NC = 64 / P;
    int ch0 = part * NC, ch1 = ch0 + NC;

    const _Float16* loopT  = pass ? x2t : x1t;
    const _Float16* blockT = pass ? x1t : x2t;
    const unsigned short* loopFt = pass ? x2ft : x1ft;
    float* accPo = pass ? accP2 : accP1;
    float* cso   = pass ? cs2   : cs1;

    const _Float16* lT = loopT + (size_t)b * HWSZ * CCH;
    const _Float16* bT = blockT + (size_t)b * HWSZ * CCH;
    const unsigned short* lFt = loopFt + (size_t)b * 524288;

    // hoist gram B frags: col = slice*128 + mh*32 + tt*16 + l16, K=128
    half8 bfrag[2][4];
    #pragma unroll
    for (int tt = 0; tt < 2; ++tt)
        #pragma unroll
        for (int ks = 0; ks < 4; ++ks)
            bfrag[tt][ks] = *(const half8*)&bT[
                (size_t)(slice * 128 + mh * 32 + tt * 16 + l16) * CCH + ks * 32 + lg * 8];

    // AF staging via global_load_lds: LDS unit u=tid gets row=u>>4,
    // src seg = (u&15)^(row&7)  (pre-swizzled source, linear LDS dest)
    int prow = tid >> 4, psw = tid & 15;
    const _Float16* af_src = lT + (size_t)prow * CCH + (psw ^ (prow & 7)) * 8;

    // paf global base: unit (t*8 + (nt*2+ci))*2 + kf, + lane*8 ushorts
    const unsigned short* pafb = lFt + (size_t)lane * 8 + (size_t)(nt * 2) * 1024;

    float csum0 = 0.f, csum1 = 0.f;
    floatx4 accP[2][2];
    #pragma unroll
    for (int ci = 0; ci < 2; ++ci)
        #pragma unroll
        for (int cj = 0; cj < 2; ++cj) accP[ci][cj] = (floatx4){0.f, 0.f, 0.f, 0.f};

    // E-tile write addresses (loop-invariant)
    int wo0 = (mh * 32 + l16) * 64 + (((nt * 2 + (lg >> 1)) ^ swz) << 3) + ((lg & 1) << 2);
    int wo1 = wo0 + 16 * 64;

    // ---- prologue: stage AF(ch0); gram(ch0); EB[ch0] write; stage AF(ch0+1)
    GLDS(af_src + (size_t)ch0 * 64 * CCH, &AF[ch0 & 1][tid * 8]);
    FBARV();
    {
        int t = ch0;
        if (t + 1 < ch1)
            GLDS(af_src + (size_t)(t + 1) * 64 * CCH, &AF[(t + 1) & 1][tid * 8]);
        half8 afr[4];
        #pragma unroll
        for (int ks = 0; ks < 4; ++ks)
            afr[ks] = *(const half8*)&AF[t & 1][
                ((nt * 16 + l16) * 16 + ((ks * 4 + lg) ^ swz)) * 8];
        floatx4 accA0 = {0.f, 0.f, 0.f, 0.f}, accA1 = {0.f, 0.f, 0.f, 0.f};
        #pragma unroll
        for (int ks = 0; ks < 4; ++ks) {
            accA0 = __builtin_amdgcn_mfma_f32_16x16x32_f16(afr[ks], bfrag[0][ks], accA0, 0, 0, 0);
            accA1 = __builtin_amdgcn_mfma_f32_16x16x32_f16(afr[ks], bfrag[1][ks], accA1, 0, 0, 0);
        }
        float v00 = __expf(accA0[0]), v01 = __expf(accA0[1]);
        float v02 = __expf(accA0[2]), v03 = __expf(accA0[3]);
        float v10 = __expf(accA1[0]), v11 = __expf(accA1[1]);
        float v12 = __expf(accA1[2]), v13 = __expf(accA1[3]);
        csum0 += (v00 + v01) + (v02 + v03);
        csum1 += (v10 + v11) + (v12 + v13);
        uint2v e0 = (uint2v){cvtpk(v00, v01), cvtpk(v02, v03)};
        uint2v e1 = (uint2v){cvtpk(v10, v11), cvtpk(v12, v13)};
        *(uint2v*)&EB[t & 1][wo0] = e0;
        *(uint2v*)&EB[t & 1][wo1] = e1;
        FBARV();   // barrier(ch0): EB[ch0], AF[ch0+1] ready
    }

    // ---- steady state: one barrier per chunk
    for (int t = ch0 + 1; t < ch1; ++t) {
        // paf(t-1) fragment loads (coalesced b128 from tiled global)
        short8 paf[2][2];
        #pragma unroll
        for (int ci = 0; ci < 2; ++ci)
            #pragma unroll
            for (int kf = 0; kf < 2; ++kf)
                paf[ci][kf] = *(const short8*)&pafb[
                    (size_t)(t - 1) * 8192 + (size_t)(ci * 2 + kf) * 512];
        // stage AF(t+1) (DMA; drained by this segment's FBARV)
        if (t + 1 < ch1)
            GLDS(af_src + (size_t)(t + 1) * 64 * CCH, &AF[(t + 1) & 1][tid * 8]);
        // gram(t): rows nt*16.., cols mh*32 + {0,16} + l16, K=128 (fp16)
        half8 afr[4];
        #pragma unroll
        for (int ks = 0; ks < 4; ++ks)
            afr[ks] = *(const half8*)&AF[t & 1][
                ((nt * 16 + l16) * 16 + ((ks * 4 + lg) ^ swz)) * 8];
        floatx4 accA0 = {0.f, 0.f, 0.f, 0.f}, accA1 = {0.f, 0.f, 0.f, 0.f};
        #pragma unroll
        for (int ks = 0; ks < 4; ++ks) {
            accA0 = __builtin_amdgcn_mfma_f32_16x16x32_f16(afr[ks], bfrag[0][ks], accA0, 0, 0, 0);
            accA1 = __builtin_amdgcn_mfma_f32_16x16x32_f16(afr[ks], bfrag[1][ks], accA1, 0, 0, 0);
        }
        // exp(t) + pack + colsum
        float v00 = __expf(accA0[0]), v01 = __expf(accA0[1]);
        float v02 = __expf(accA0[2]), v03 = __expf(accA0[3]);
        float v10 = __expf(accA1[0]), v11 = __expf(accA1[1]);
        float v12 = __expf(accA1[2]), v13 = __expf(accA1[3]);
        csum0 += (v00 + v01) + (v02 + v03);
        csum1 += (v10 + v11) + (v12 + v13);
        uint2v e0 = (uint2v){cvtpk(v00, v01), cvtpk(v02, v03)};
        uint2v e1 = (uint2v){cvtpk(v10, v11), cvtpk(v12, v13)};
        *(uint2v*)&EB[t & 1][wo0] = e0;
        *(uint2v*)&EB[t & 1][wo1] = e1;
        // PV(t-1): reads EB[(t-1)&1] (visible since barrier t-1)
        #pragma unroll
        for (int kf = 0; kf < 2; ++kf) {
            short8 ebf[2];
            #pragma unroll
            for (int cj = 0; cj < 2; ++cj) {
                int ecol = (mh * 2 + cj) * 16 + l16;
                ebf[cj] = *(const short8*)&EB[(t - 1) & 1][
                    ecol * 64 + (((kf * 4 + lg) ^ swz) << 3)];
            }
            #pragma unroll
            for (int ci = 0; ci < 2; ++ci)
                #pragma unroll
                for (int cj = 0; cj < 2; ++cj)
                    accP[ci][cj] = __builtin_amdgcn_mfma_f32_16x16x32_bf16(
                        paf[ci][kf], ebf[cj], accP[ci][cj], 0, 0, 0);
        }
        FBARV();   // barrier(t): EB[t], AF[t+1] ready; all reads drained
    }

    // ---- epilogue: PV(ch1-1)
    {
        int t = ch1 - 1;
        short8 paf[2][2];
        #pragma unroll
        for (int ci = 0; ci < 2; ++ci)
            #pragma unroll
            for (int kf = 0; kf < 2; ++kf)
                paf[ci][kf] = *(const short8*)&pafb[
                    (size_t)t * 8192 + (size_t)(ci * 2 + kf) * 512];
        #pragma unroll
        for (int kf = 0; kf < 2; ++kf) {
            short8 ebf[2];
            #pragma unroll
            for (int cj = 0; cj < 2; ++cj) {
                int ecol = (mh * 2 + cj) * 16 + l16;
                ebf[cj] = *(const short8*)&EB[t & 1][
                    ecol * 64 + (((kf * 4 + lg) ^ swz) << 3)];
            }
            #pragma unroll
            for (int ci = 0; ci < 2; ++ci)
                #pragma unroll
                for (int cj = 0; cj < 2; ++cj)
                    accP[ci][cj] = __builtin_amdgcn_mfma_f32_16x16x32_bf16(
                        paf[ci][kf], ebf[cj], accP[ci][cj], 0, 0, 0);
        }
    }
    __syncthreads();   // drain all reads before aliasing EB

    // ---- colsum: deterministic cross-wave reduce (alias scratch onto EB)
    float* cspart = (float*)EB;   // [4][128]
    float v = csum0;
    v += __shfl_xor(v, 16, 64); v += __shfl_xor(v, 32, 64);
    float w = csum1;
    w += __shfl_xor(w, 16, 64); w += __shfl_xor(w, 32, 64);
    if (lane < 16) {
        cspart[nt * 128 + mh * 32 + lane] = v;
        cspart[nt * 128 + mh * 32 + 16 + lane] = w;
    }
    __syncthreads();
    size_t sbase = ((size_t)part * BATCH + b) * 32 + slice;
    if (tid < 128)
        cso[sbase * 128 + tid] = cspart[tid] + cspart[128 + tid] +
                                 cspart[256 + tid] + cspart[384 + tid];

    // ---- store partial accP: c = (nt*2+ci)*16 + lg*4 + rr, col = (mh*2+cj)*16 + l16
    float* po = accPo + sbase * (128 * 128);
    #pragma unroll
    for (int ci = 0; ci < 2; ++ci)
        #pragma unroll
        for (int cj = 0; cj < 2; ++cj)
            #pragma unroll
            for (int rr = 0; rr < 4; ++rr)
                po[(size_t)((nt * 2 + ci) * 16 + lg * 4 + rr) * 128 +
                   (mh * 2 + cj) * 16 + l16] = accP[ci][cj][rr];
}

// merged epilogue: one block per (b, 64-col strip); computes BOTH passes'
// contributions and writes out once.
__global__ __launch_bounds__(512) void combine2_kernel(
    const float* __restrict__ accP1, const float* __restrict__ cs1,
    const float* __restrict__ accP2, const float* __restrict__ cs2,
    const float* __restrict__ x1, const float* __restrict__ x2,
    const float* __restrict__ gw, const float* __restrict__ cwp,
    float* __restrict__ out, int P)
{
    __shared__ float red[512];
    __shared__ float gws[CCH];
    int b = blockIdx.x >> 6, s2 = blockIdx.x & 63;   // 64-col strip
    int tid = threadIdx.x;
    if (tid < CCH) gws[tid] = gw[tid];
    __syncthreads();
    int c64 = tid & 63, cg = tid >> 6;    // 8 c-groups x 16 c
    int slice = s2 >> 1;
    int colin = (s2 & 1) * 64 + c64;      // col within 128-col slice
    int colg  = s2 * 64 + c64;            // global col
    float d1 = 0.f, d2 = 0.f;
    for (int p = 0; p < P; ++p) {
        size_t sb = (((size_t)p * BATCH + b) * 32 + slice) * 128;
        d1 += cs1[sb + colin];
        d2 += cs2[sb + colin];
    }
    float inv1 = 1.f / d1, inv2 = 1.f / d2;
    float acc = 0.f;
    #pragma unroll 4
    for (int ci = 0; ci < 16; ++ci) {
        int c = cg * 16 + ci;
        size_t fo = (size_t)c * 128 + colin;
        float s1 = 0.f, s2v = 0.f;
        for (int p = 0; p < P; ++p) {
            size_t sb = ((((size_t)p * BATCH + b) * 32 + slice) * (size_t)128) * 128;
            s1  += accP1[sb + fo];
            s2v += accP2[sb + fo];
        }
        float a1 = s1 * inv1, a2 = s2v * inv2;
        float m1 = 1.f / (1.f + __expf(-a1));
        float m2 = 1.f / (1.f + __expf(-a2));
        size_t xei = ((size_t)b * CCH + c) * HWSZ + colg;
        acc += gws[c] * (m1 * x2[xei] + m2 * x1[xei]);
    }
    red[tid] = acc;
    __syncthreads();
    if (tid < 64) {
        float t = 0.f;
        #pragma unroll
        for (int g = 0; g < 8; ++g) t += red[tid + 64 * g];
        out[(size_t)b * HWSZ + s2 * 64 + tid] = cwp[0] * t;
    }
}

// single-pass combine (fallback when workspace can't hold both passes)
template<int ACCUM>
__global__ __launch_bounds__(256) void combine_kernel(
    const float* __restrict__ accPp, const float* __restrict__ csp,
    const float* __restrict__ xe, const float* __restrict__ gw,
    const float* __restrict__ cwp, float* __restrict__ out, int P)
{
    __shared__ float red[256];
    __shared__ float gws[CCH];
    int b = blockIdx.x >> 5, slice = blockIdx.x & 31;
    int tid = threadIdx.x;
    if (tid < CCH) gws[tid] = gw[tid];
    __syncthreads();
    int col = tid & 127, half = tid >> 7;
    float cs = 0.f;
    for (int p = 0; p < P; ++p)
        cs += csp[(((size_t)p * BATCH + b) * 32 + slice) * 128 + col];
    float inv = 1.f / cs;
    float acc = 0.f;
    for (int ci = 0; ci < 64; ++ci) {
        int c = half * 64 + ci;
        float s = 0.f;
        for (int p = 0; p < P; ++p)
            s += accPp[((((size_t)p * BATCH + b) * 32 + slice) * 128 + c) * 128 + col];
        float att = s * inv;
        float mask = 1.f / (1.f + __expf(-att));
        acc += gws[c] * mask * xe[((size_t)b * CCH + c) * HWSZ + slice * 128 + col];
    }
    red[tid] = acc;
    __syncthreads();
    if (tid < 128) {
        float vv = cwp[0] * (red[tid] + red[tid + 128]);
        size_t o = (size_t)b * HWSZ + slice * 128 + tid;
        if (ACCUM) out[o] += vv; else out[o] = vv;
    }
}

extern "C" void kernel_launch(void* const* d_in, const int* in_sizes, int n_in,
                              void* d_out, int out_size, void* d_ws, size_t ws_size,
                              hipStream_t stream) {
    const float* x1 = (const float*)d_in[0];
    const float* x2 = (const float*)d_in[1];
    const float* gw = (const float*)d_in[2];
    const float* cw = (const float*)d_in[3];
    float* out = (float*)d_out;

    char* ws = (char*)d_ws;
    size_t elems = (size_t)BATCH * CCH * HWSZ;  // 2M
    _Float16* x1t = (_Float16*)ws;
    _Float16* x2t = (_Float16*)(ws + elems * 2);
    unsigned short* x1ft = (unsigned short*)(ws + elems * 4);
    unsigned short* x2ft = (unsigned short*)(ws + elems * 6);
    char* pbase = ws + elems * 8;               // 16 MB used by prep arrays

    // partials per pass: accP P*B*32*128*128*4 + cs P*B*32*128*4
    auto region = [](int P) {
        return (size_t)P * BATCH * 32 * 128 * 128 * 4 +
               (size_t)P * BATCH * 32 * 128 * 4;
    };
    size_t avail = (ws_size > elems * 8) ? ws_size - elems * 8 : 0;
    int P; bool dual;
    if      (avail >= 2 * region(2)) { P = 2; dual = true;  }
    else if (avail >=     region(2)) { P = 2; dual = false; }
    else                             { P = 1; dual = false; }

    size_t accPbytes = (size_t)P * BATCH * 32 * 128 * 128 * 4;
    float* accP1 = (float*)pbase;
    float* cs1   = (float*)(pbase + accPbytes);
    float* accP2 = dual ? (float*)(pbase + region(P)) : accP1;
    float* cs2   = dual ? (float*)(pbase + region(P) + accPbytes) : cs1;

    prep_kernel<<<4096, 256, 0, stream>>>(x1, x2, x1t, x2t, x1ft, x2ft);

    if (dual) {
        // BOTH passes in one launch.
        fused_part<<<2 * 128 * P, 1024, 0, stream>>>(
            x1t, x2t, x1ft, x2ft, accP1, cs1, accP2, cs2, P, -1);
        combine2_kernel<<<BATCH * 64, 512, 0, stream>>>(
            accP1, cs1, accP2, cs2, x1, x2, gw, cw, out, P);
    } else {
        fused_part<<<128 * P, 1024, 0, stream>>>(
            x1t, x2t, x1ft, x2ft, accP1, cs1, accP1, cs1, P, 0);
        combine_kernel<0><<<BATCH * 32, 256, 0, stream>>>(accP1, cs1, x2, gw, cw, out, P);
        fused_part<<<128 * P, 1024, 0, stream>>>(
            x1t, x2t, x1ft, x2ft, accP1, cs1, accP1, cs1, P, 1);
        combine_kernel<1><<<BATCH * 32, 256, 0, stream>>>(accP1, cs1, x1, gw, cw, out, P);
    }
}

// Round 12
// 122.077 us; speedup vs baseline: 1.0499x; 1.0499x over previous
//
#include <hip/hip_runtime.h>
#include <hip/hip_fp16.h>

// Problem constants (B=4, C=128, H=W=64 -> HW=4096)
#define BATCH 4
#define CCH   128
#define HWSZ  4096

typedef _Float16 half8 __attribute__((ext_vector_type(8)));
typedef short short8 __attribute__((ext_vector_type(8)));
typedef unsigned short ushort8 __attribute__((ext_vector_type(8)));
typedef float floatx4 __attribute__((ext_vector_type(4)));
typedef unsigned int uint2v __attribute__((ext_vector_type(2)));

__device__ __forceinline__ unsigned short f2bf(float f) {
    union { float f; unsigned u; } v; v.f = f;
    return (unsigned short)((v.u + 0x7fffu + ((v.u >> 16) & 1u)) >> 16);
}

// pack 2 f32 -> 2 bf16 in one dword (low = a, high = b)
__device__ __forceinline__ unsigned cvtpk(float a, float b) {
    unsigned r;
    asm("v_cvt_pk_bf16_f32 %0, %1, %2" : "=v"(r) : "v"(a), "v"(b));
    return r;
}

// raw barrier: LDS drain + barrier, NO vmcnt drain — global loads keep
// compiler-placed per-wave counted waits (no gang drain; R11 lesson).
#define FBAR() do { __builtin_amdgcn_sched_barrier(0); \
    asm volatile("s_waitcnt lgkmcnt(0)" ::: "memory"); \
    __builtin_amdgcn_s_barrier(); \
    __builtin_amdgcn_sched_barrier(0); } while (0)

// prep: x fp32 [B][C][HW] ->
//   xt  fp16 [B][HW][C]  (transposed, for gram A staging)
//   xft bf16 MFMA-A-fragment-tiled: per batch, unit u = (t*8+ct)*2+kf holds
//     512 ushorts: lane (l16=c&15, lg)*8 + j  = A[c][k=lg*8+j] of chunk t,
//     c-tile ct, k-half kf. Fused paf load = base + lane*16B (coalesced b128).
__global__ __launch_bounds__(256) void prep_kernel(
    const float* __restrict__ x1, const float* __restrict__ x2,
    _Float16* __restrict__ x1t, _Float16* __restrict__ x2t,
    unsigned short* __restrict__ x1ft, unsigned short* __restrict__ x2ft)
{
    __shared__ float lds[32][33];
    int idx = blockIdx.x;            // 0..4095
    int which = idx >> 11;           // 0: x1, 1: x2
    int r = idx & 2047;
    int cb  = r & 3;                 // C/32  = 4
    int hwb = (r >> 2) & 127;        // HW/32 = 128
    int b   = r >> 9;                // 4 batches
    const float* x = which ? x2 : x1;
    _Float16* xt = which ? x2t : x1t;
    unsigned short* xft = which ? x2ft : x1ft;
    int tid = threadIdx.x;
    int tc = tid >> 5, th = tid & 31;
    #pragma unroll
    for (int k = 0; k < 4; ++k) {
        int cl = tc + 8 * k;
        lds[cl][th] = x[((size_t)b * CCH + cb * 32 + cl) * HWSZ + hwb * 32 + th];
    }
    __syncthreads();
    // xt transpose store
    #pragma unroll
    for (int k = 0; k < 4; ++k) {
        int hl = tc + 8 * k;
        xt[((size_t)b * HWSZ + hwb * 32 + hl) * CCH + cb * 32 + th] =
            (_Float16)lds[th][hl];
    }
    // xft tiled store: 128 units of 16B (32 c x 4 segs)
    if (tid < 128) {
        int c_local = tid >> 2, seg = tid & 3;
        int c = cb * 32 + c_local;
        int ct = c >> 4, l16c = c & 15;
        int t = hwb >> 1, kf = hwb & 1;
        ushort8 v;
        #pragma unroll
        for (int j = 0; j < 8; ++j) v[j] = f2bf(lds[c_local][seg * 8 + j]);
        size_t ui = ((((size_t)t * 8 + ct) * 2 + kf) * 64 + seg * 16 + l16c) * 8;
        *(ushort8*)&xft[(size_t)b * 524288 + ui] = v;
    }
}

// Fused partial pass (BOTH softmax passes in one launch), col-tile = 128,
// 16 waves, 64KB LDS (2 blocks/CU). R10 body with AF[2]+EB[2] double
// buffers -> ONE lgkm-only barrier per chunk; PV lags one chunk.
// Segment t (between barrier t-1 and barrier t):
//   issue ga(t+1) [global->reg], paf(t-1) [tiled-global frags]
//   gram(t) reads AF[t&1]; exp(t); write EB[t&1]
//   ds_write AF[(t+1)&1] <- ga   (vmcnt wait per-wave, covered by segment)
//   PV(t-1): paf(t-1) x EB[(t-1)&1]
//   FBAR (lgkm only)
// Race proof (lgkm barrier): each buffer's readers drain own ds ops at
// barrier t; that buffer's next writer writes only after barrier t:
//   AF[t&1] read seg t / rewritten seg t+1; AF[(t+1)&1] written seg t,
//   read seg t+1; EB[t&1] written seg t, read seg t+1; EB[(t-1)&1] read
//   seg t, rewritten seg t+1.  All satisfied.
__global__ __launch_bounds__(1024, 4) void fused_part(
    const _Float16* __restrict__ x1t, const _Float16* __restrict__ x2t,
    const unsigned short* __restrict__ x1ft, const unsigned short* __restrict__ x2ft,
    float* __restrict__ accP1, float* __restrict__ cs1,
    float* __restrict__ accP2, float* __restrict__ cs2,
    int P, int passSel)
{
    __shared__ unsigned short AF[2][8192];   // 64 rows x 128 c fp16, swizzled
    __shared__ unsigned short EB[2][8192];   // 128 cols x 64 rows bf16, swizzled

    int bid = blockIdx.x;
    int pass, bidp;
    if (passSel < 0) { pass = bid >> 8; bidp = bid & 255; }
    else             { pass = passSel;  bidp = bid; }
    int xcd = bidp & 7, grp = bidp >> 3;  // grp 0..16P-1
    int b = xcd >> 1;                     // 2 XCDs per batch (L2 locality)
    int slice = (grp & 15) + 16 * (xcd & 1);   // 0..31 (128 cols each)
    int part = grp >> 4;                  // 0..P-1
    int tid = threadIdx.x;
    int wave = tid >> 6, lane = tid & 63;
    int l16 = lane & 15, lg = lane >> 4;
    int nt = wave & 3, mh = wave >> 2;    // gram: row-tile nt, col-32-group mh
    int swz = l16 & 7;
    int NC = 64 / P;
    int ch0 = part * NC, ch1 = ch0 + NC;

    const _Float16* loopT  = pass ? x2t : x1t;
    const _Float16* blockT = pass ? x1t : x2t;
    const unsigned short* loopFt = pass ? x2ft : x1ft;
    float* accPo = pass ? accP2 : accP1;
    float* cso   = pass ? cs2   : cs1;

    const _Float16* lT = loopT + (size_t)b * HWSZ * CCH;
    const _Float16* bT = blockT + (size_t)b * HWSZ * CCH;
    const unsigned short* lFt = loopFt + (size_t)b * 524288;

    // hoist gram B frags: col = slice*128 + mh*32 + tt*16 + l16, K=128
    half8 bfrag[2][4];
    #pragma unroll
    for (int tt = 0; tt < 2; ++tt)
        #pragma unroll
        for (int ks = 0; ks < 4; ++ks)
            bfrag[tt][ks] = *(const half8*)&bT[
                (size_t)(slice * 128 + mh * 32 + tt * 16 + l16) * CCH + ks * 32 + lg * 8];

    // AF staging: thread owns one 16B unit. row=tid>>4, s=tid&15.
    // LDS unit = row*16 + (s ^ (row&7)) -> conflict-free b128 frag reads.
    int arow = tid >> 4, as_ = tid & 15;
    const _Float16* afsrc = lT + (size_t)arow * CCH + as_ * 8;
    int afw = (arow * 16 + (as_ ^ (arow & 7))) * 8;      // ushort index

    // paf global base: unit (t*8 + (nt*2+ci))*2 + kf, + lane*8 ushorts
    const unsigned short* pafb = lFt + (size_t)lane * 8 + (size_t)(nt * 2) * 1024;

    float csum0 = 0.f, csum1 = 0.f;
    floatx4 accP[2][2];
    #pragma unroll
    for (int ci = 0; ci < 2; ++ci)
        #pragma unroll
        for (int cj = 0; cj < 2; ++cj) accP[ci][cj] = (floatx4){0.f, 0.f, 0.f, 0.f};

    // E-tile write addresses (loop-invariant)
    int wo0 = (mh * 32 + l16) * 64 + (((nt * 2 + (lg >> 1)) ^ swz) << 3) + ((lg & 1) << 2);
    int wo1 = wo0 + 16 * 64;

    // ---- prologue: stage AF(ch0); then segment ch0 (no PV)
    {
        floatx4 ga0 = *(const floatx4*)(afsrc + (size_t)ch0 * 64 * CCH);
        *(floatx4*)&AF[ch0 & 1][afw] = ga0;
    }
    __syncthreads();
    {
        int t = ch0;
        floatx4 ga = *(const floatx4*)(afsrc + (size_t)(t + 1 < ch1 ? t + 1 : t) * 64 * CCH);
        half8 afr[4];
        #pragma unroll
        for (int ks = 0; ks < 4; ++ks)
            afr[ks] = *(const half8*)&AF[t & 1][
                ((nt * 16 + l16) * 16 + ((ks * 4 + lg) ^ swz)) * 8];
        floatx4 accA0 = {0.f, 0.f, 0.f, 0.f}, accA1 = {0.f, 0.f, 0.f, 0.f};
        #pragma unroll
        for (int ks = 0; ks < 4; ++ks) {
            accA0 = __builtin_amdgcn_mfma_f32_16x16x32_f16(afr[ks], bfrag[0][ks], accA0, 0, 0, 0);
            accA1 = __builtin_amdgcn_mfma_f32_16x16x32_f16(afr[ks], bfrag[1][ks], accA1, 0, 0, 0);
        }
        float v00 = __expf(accA0[0]), v01 = __expf(accA0[1]);
        float v02 = __expf(accA0[2]), v03 = __expf(accA0[3]);
        float v10 = __expf(accA1[0]), v11 = __expf(accA1[1]);
        float v12 = __expf(accA1[2]), v13 = __expf(accA1[3]);
        csum0 += (v00 + v01) + (v02 + v03);
        csum1 += (v10 + v11) + (v12 + v13);
        uint2v e0 = (uint2v){cvtpk(v00, v01), cvtpk(v02, v03)};
        uint2v e1 = (uint2v){cvtpk(v10, v11), cvtpk(v12, v13)};
        *(uint2v*)&EB[t & 1][wo0] = e0;
        *(uint2v*)&EB[t & 1][wo1] = e1;
        *(floatx4*)&AF[(t + 1) & 1][afw] = ga;   // AF(ch0+1)
        FBAR();   // barrier(ch0)
    }

    // ---- steady state: one lgkm-only barrier per chunk
    for (int t = ch0 + 1; t < ch1; ++t) {
        // issue ga(t+1) and paf(t-1) early (per-wave counted waits at use)
        floatx4 ga = *(const floatx4*)(afsrc + (size_t)(t + 1 < ch1 ? t + 1 : t) * 64 * CCH);
        short8 paf[2][2];
        #pragma unroll
        for (int ci = 0; ci < 2; ++ci)
            #pragma unroll
            for (int kf = 0; kf < 2; ++kf)
                paf[ci][kf] = *(const short8*)&pafb[
                    (size_t)(t - 1) * 8192 + (size_t)(ci * 2 + kf) * 512];
        // gram(t): rows nt*16.., cols mh*32 + {0,16} + l16, K=128 (fp16)
        half8 afr[4];
        #pragma unroll
        for (int ks = 0; ks < 4; ++ks)
            afr[ks] = *(const half8*)&AF[t & 1][
                ((nt * 16 + l16) * 16 + ((ks * 4 + lg) ^ swz)) * 8];
        floatx4 accA0 = {0.f, 0.f, 0.f, 0.f}, accA1 = {0.f, 0.f, 0.f, 0.f};
        #pragma unroll
        for (int ks = 0; ks < 4; ++ks) {
            accA0 = __builtin_amdgcn_mfma_f32_16x16x32_f16(afr[ks], bfrag[0][ks], accA0, 0, 0, 0);
            accA1 = __builtin_amdgcn_mfma_f32_16x16x32_f16(afr[ks], bfrag[1][ks], accA1, 0, 0, 0);
        }
        // exp(t) + pack + colsum
        float v00 = __expf(accA0[0]), v01 = __expf(accA0[1]);
        float v02 = __expf(accA0[2]), v03 = __expf(accA0[3]);
        float v10 = __expf(accA1[0]), v11 = __expf(accA1[1]);
        float v12 = __expf(accA1[2]), v13 = __expf(accA1[3]);
        csum0 += (v00 + v01) + (v02 + v03);
        csum1 += (v10 + v11) + (v12 + v13);
        uint2v e0 = (uint2v){cvtpk(v00, v01), cvtpk(v02, v03)};
        uint2v e1 = (uint2v){cvtpk(v10, v11), cvtpk(v12, v13)};
        *(uint2v*)&EB[t & 1][wo0] = e0;
        *(uint2v*)&EB[t & 1][wo1] = e1;
        // AF(t+1) staging write (AF[t&1] readers are THIS segment, other buf)
        *(floatx4*)&AF[(t + 1) & 1][afw] = ga;
        // PV(t-1): reads EB[(t-1)&1] (visible since barrier t-1)
        #pragma unroll
        for (int kf = 0; kf < 2; ++kf) {
            short8 ebf[2];
            #pragma unroll
            for (int cj = 0; cj < 2; ++cj) {
                int ecol = (mh * 2 + cj) * 16 + l16;
                ebf[cj] = *(const short8*)&EB[(t - 1) & 1][
                    ecol * 64 + (((kf * 4 + lg) ^ swz) << 3)];
            }
            #pragma unroll
            for (int ci = 0; ci < 2; ++ci)
                #pragma unroll
                for (int cj = 0; cj < 2; ++cj)
                    accP[ci][cj] = __builtin_amdgcn_mfma_f32_16x16x32_bf16(
                        paf[ci][kf], ebf[cj], accP[ci][cj], 0, 0, 0);
        }
        FBAR();   // barrier(t): EB[t], AF[t+1] visible; all ds reads drained
    }

    // ---- epilogue: PV(ch1-1)
    {
        int t = ch1 - 1;
        short8 paf[2][2];
        #pragma unroll
        for (int ci = 0; ci < 2; ++ci)
            #pragma unroll
            for (int kf = 0; kf < 2; ++kf)
                paf[ci][kf] = *(const short8*)&pafb[
                    (size_t)t * 8192 + (size_t)(ci * 2 + kf) * 512];
        #pragma unroll
        for (int kf = 0; kf < 2; ++kf) {
            short8 ebf[2];
            #pragma unroll
            for (int cj = 0; cj < 2; ++cj) {
                int ecol = (mh * 2 + cj) * 16 + l16;
                ebf[cj] = *(const short8*)&EB[t & 1][
                    ecol * 64 + (((kf * 4 + lg) ^ swz) << 3)];
            }
            #pragma unroll
            for (int ci = 0; ci < 2; ++ci)
                #pragma unroll
                for (int cj = 0; cj < 2; ++cj)
                    accP[ci][cj] = __builtin_amdgcn_mfma_f32_16x16x32_bf16(
                        paf[ci][kf], ebf[cj], accP[ci][cj], 0, 0, 0);
        }
    }
    __syncthreads();   // drain all reads before aliasing EB

    // ---- colsum: deterministic cross-wave reduce (alias scratch onto EB)
    float* cspart = (float*)EB;   // [4][128]
    float v = csum0;
    v += __shfl_xor(v, 16, 64); v += __shfl_xor(v, 32, 64);
    float w = csum1;
    w += __shfl_xor(w, 16, 64); w += __shfl_xor(w, 32, 64);
    if (lane < 16) {
        cspart[nt * 128 + mh * 32 + lane] = v;
        cspart[nt * 128 + mh * 32 + 16 + lane] = w;
    }
    __syncthreads();
    size_t sbase = ((size_t)part * BATCH + b) * 32 + slice;
    if (tid < 128)
        cso[sbase * 128 + tid] = cspart[tid] + cspart[128 + tid] +
                                 cspart[256 + tid] + cspart[384 + tid];

    // ---- store partial accP: c = (nt*2+ci)*16 + lg*4 + rr, col = (mh*2+cj)*16 + l16
    float* po = accPo + sbase * (128 * 128);
    #pragma unroll
    for (int ci = 0; ci < 2; ++ci)
        #pragma unroll
        for (int cj = 0; cj < 2; ++cj)
            #pragma unroll
            for (int rr = 0; rr < 4; ++rr)
                po[(size_t)((nt * 2 + ci) * 16 + lg * 4 + rr) * 128 +
                   (mh * 2 + cj) * 16 + l16] = accP[ci][cj][rr];
}

// merged epilogue: one block per (b, 64-col strip); computes BOTH passes'
// contributions and writes out once.
__global__ __launch_bounds__(512) void combine2_kernel(
    const float* __restrict__ accP1, const float* __restrict__ cs1,
    const float* __restrict__ accP2, const float* __restrict__ cs2,
    const float* __restrict__ x1, const float* __restrict__ x2,
    const float* __restrict__ gw, const float* __restrict__ cwp,
    float* __restrict__ out, int P)
{
    __shared__ float red[512];
    __shared__ float gws[CCH];
    int b = blockIdx.x >> 6, s2 = blockIdx.x & 63;   // 64-col strip
    int tid = threadIdx.x;
    if (tid < CCH) gws[tid] = gw[tid];
    __syncthreads();
    int c64 = tid & 63, cg = tid >> 6;    // 8 c-groups x 16 c
    int slice = s2 >> 1;
    int colin = (s2 & 1) * 64 + c64;      // col within 128-col slice
    int colg  = s2 * 64 + c64;            // global col
    float d1 = 0.f, d2 = 0.f;
    for (int p = 0; p < P; ++p) {
        size_t sb = (((size_t)p * BATCH + b) * 32 + slice) * 128;
        d1 += cs1[sb + colin];
        d2 += cs2[sb + colin];
    }
    float inv1 = 1.f / d1, inv2 = 1.f / d2;
    float acc = 0.f;
    #pragma unroll 4
    for (int ci = 0; ci < 16; ++ci) {
        int c = cg * 16 + ci;
        size_t fo = (size_t)c * 128 + colin;
        float s1 = 0.f, s2v = 0.f;
        for (int p = 0; p < P; ++p) {
            size_t sb = ((((size_t)p * BATCH + b) * 32 + slice) * (size_t)128) * 128;
            s1  += accP1[sb + fo];
            s2v += accP2[sb + fo];
        }
        float a1 = s1 * inv1, a2 = s2v * inv2;
        float m1 = 1.f / (1.f + __expf(-a1));
        float m2 = 1.f / (1.f + __expf(-a2));
        size_t xei = ((size_t)b * CCH + c) * HWSZ + colg;
        acc += gws[c] * (m1 * x2[xei] + m2 * x1[xei]);
    }
    red[tid] = acc;
    __syncthreads();
    if (tid < 64) {
        float t = 0.f;
        #pragma unroll
        for (int g = 0; g < 8; ++g) t += red[tid + 64 * g];
        out[(size_t)b * HWSZ + s2 * 64 + tid] = cwp[0] * t;
    }
}

// single-pass combine (fallback when workspace can't hold both passes)
template<int ACCUM>
__global__ __launch_bounds__(256) void combine_kernel(
    const float* __restrict__ accPp, const float* __restrict__ csp,
    const float* __restrict__ xe, const float* __restrict__ gw,
    const float* __restrict__ cwp, float* __restrict__ out, int P)
{
    __shared__ float red[256];
    __shared__ float gws[CCH];
    int b = blockIdx.x >> 5, slice = blockIdx.x & 31;
    int tid = threadIdx.x;
    if (tid < CCH) gws[tid] = gw[tid];
    __syncthreads();
    int col = tid & 127, half = tid >> 7;
    float cs = 0.f;
    for (int p = 0; p < P; ++p)
        cs += csp[(((size_t)p * BATCH + b) * 32 + slice) * 128 + col];
    float inv = 1.f / cs;
    float acc = 0.f;
    for (int ci = 0; ci < 64; ++ci) {
        int c = half * 64 + ci;
        float s = 0.f;
        for (int p = 0; p < P; ++p)
            s += accPp[((((size_t)p * BATCH + b) * 32 + slice) * 128 + c) * 128 + col];
        float att = s * inv;
        float mask = 1.f / (1.f + __expf(-att));
        acc += gws[c] * mask * xe[((size_t)b * CCH + c) * HWSZ + slice * 128 + col];
    }
    red[tid] = acc;
    __syncthreads();
    if (tid < 128) {
        float vv = cwp[0] * (red[tid] + red[tid + 128]);
        size_t o = (size_t)b * HWSZ + slice * 128 + tid;
        if (ACCUM) out[o] += vv; else out[o] = vv;
    }
}

extern "C" void kernel_launch(void* const* d_in, const int* in_sizes, int n_in,
                              void* d_out, int out_size, void* d_ws, size_t ws_size,
                              hipStream_t stream) {
    const float* x1 = (const float*)d_in[0];
    const float* x2 = (const float*)d_in[1];
    const float* gw = (const float*)d_in[2];
    const float* cw = (const float*)d_in[3];
    float* out = (float*)d_out;

    char* ws = (char*)d_ws;
    size_t elems = (size_t)BATCH * CCH * HWSZ;  // 2M
    _Float16* x1t = (_Float16*)ws;
    _Float16* x2t = (_Float16*)(ws + elems * 2);
    unsigned short* x1ft = (unsigned short*)(ws + elems * 4);
    unsigned short* x2ft = (unsigned short*)(ws + elems * 6);
    char* pbase = ws + elems * 8;               // 16 MB used by prep arrays

    // partials per pass: accP P*B*32*128*128*4 + cs P*B*32*128*4
    auto region = [](int P) {
        return (size_t)P * BATCH * 32 * 128 * 128 * 4 +
               (size_t)P * BATCH * 32 * 128 * 4;
    };
    size_t avail = (ws_size > elems * 8) ? ws_size - elems * 8 : 0;
    int P; bool dual;
    if      (avail >= 2 * region(2)) { P = 2; dual = true;  }
    else if (avail >=     region(2)) { P = 2; dual = false; }
    else                             { P = 1; dual = false; }

    size_t accPbytes = (size_t)P * BATCH * 32 * 128 * 128 * 4;
    float* accP1 = (float*)pbase;
    float* cs1   = (float*)(pbase + accPbytes);
    float* accP2 = dual ? (float*)(pbase + region(P)) : accP1;
    float* cs2   = dual ? (float*)(pbase + region(P) + accPbytes) : cs1;

    prep_kernel<<<4096, 256, 0, stream>>>(x1, x2, x1t, x2t, x1ft, x2ft);

    if (dual) {
        // BOTH passes in one launch.
        fused_part<<<2 * 128 * P, 1024, 0, stream>>>(
            x1t, x2t, x1ft, x2ft, accP1, cs1, accP2, cs2, P, -1);
        combine2_kernel<<<BATCH * 64, 512, 0, stream>>>(
            accP1, cs1, accP2, cs2, x1, x2, gw, cw, out, P);
    } else {
        fused_part<<<128 * P, 1024, 0, stream>>>(
            x1t, x2t, x1ft, x2ft, accP1, cs1, accP1, cs1, P, 0);
        combine_kernel<0><<<BATCH * 32, 256, 0, stream>>>(accP1, cs1, x2, gw, cw, out, P);
        fused_part<<<128 * P, 1024, 0, stream>>>(
            x1t, x2t, x1ft, x2ft, accP1, cs1, accP1, cs1, P, 1);
        combine_kernel<1><<<BATCH * 32, 256, 0, stream>>>(accP1, cs1, x1, gw, cw, out, P);
    }
}

// Round 13
// 105.862 us; speedup vs baseline: 1.2107x; 1.1532x over previous
//
#include <hip/hip_runtime.h>
#include <hip/hip_fp16.h>

// Problem constants (B=4, C=128, H=W=64 -> HW=4096)
#define BATCH 4
#define CCH   128
#define HWSZ  4096

typedef _Float16 half8 __attribute__((ext_vector_type(8)));
typedef short short8 __attribute__((ext_vector_type(8)));
typedef float floatx4 __attribute__((ext_vector_type(4)));
typedef unsigned short ushort4v __attribute__((ext_vector_type(4)));
typedef unsigned int uint2v __attribute__((ext_vector_type(2)));

__device__ __forceinline__ unsigned short f2bf(float f) {
    union { float f; unsigned u; } v; v.f = f;
    return (unsigned short)((v.u + 0x7fffu + ((v.u >> 16) & 1u)) >> 16);
}

// pack 2 f32 -> 2 bf16 in one dword (low = a, high = b)
__device__ __forceinline__ unsigned cvtpk(float a, float b) {
    unsigned r;
    asm("v_cvt_pk_bf16_f32 %0, %1, %2" : "=v"(r) : "v"(a), "v"(b));
    return r;
}

// prep: x fp32 [B][C][HW] -> xt fp16 [B][HW][C] (transposed), xf bf16 [B][C][HW]
__global__ __launch_bounds__(256) void prep_kernel(
    const float* __restrict__ x1, const float* __restrict__ x2,
    _Float16* __restrict__ x1t, _Float16* __restrict__ x2t,
    unsigned short* __restrict__ x1f, unsigned short* __restrict__ x2f)
{
    __shared__ float lds[32][33];
    int idx = blockIdx.x;            // 0..4095
    int which = idx >> 11;           // 0: x1, 1: x2
    int r = idx & 2047;
    int cb  = r & 3;                 // C/32  = 4
    int hwb = (r >> 2) & 127;        // HW/32 = 128
    int b   = r >> 9;                // 4 batches
    const float* x = which ? x2 : x1;
    _Float16* xt = which ? x2t : x1t;
    unsigned short* xf = which ? x2f : x1f;
    int tid = threadIdx.x;
    int tc = tid >> 5, th = tid & 31;
    #pragma unroll
    for (int k = 0; k < 4; ++k) {
        int cl = tc + 8 * k;
        int c = cb * 32 + cl, hw = hwb * 32 + th;
        float v = x[((size_t)b * CCH + c) * HWSZ + hw];
        lds[cl][th] = v;
        xf[((size_t)b * CCH + c) * HWSZ + hw] = f2bf(v);
    }
    __syncthreads();
    #pragma unroll
    for (int k = 0; k < 4; ++k) {
        int hl = tc + 8 * k;
        xt[((size_t)b * HWSZ + hwb * 32 + hl) * CCH + cb * 32 + th] =
            (_Float16)lds[th][hl];
    }
}

// raw barrier: LDS drain + barrier, no vmcnt drain; sched fences keep the
// staging loads pinned on their issue side.
#define FBAR() do { __builtin_amdgcn_sched_barrier(0); \
    asm volatile("s_waitcnt lgkmcnt(0)" ::: "memory"); \
    __builtin_amdgcn_s_barrier(); \
    __builtin_amdgcn_sched_barrier(0); } while (0)

// Fused partial pass (BOTH softmax passes in one launch), col-tile = 128,
// 16 waves, 48KB LDS, VGPR<=64 -> 2 blocks/CU co-resident.
// Proven R7/R8 body (89.5us). ONLY change this round: T5 s_setprio(1)
// around the gram and PV MFMA clusters — with 2 co-resident blocks at
// independent barrier phases, the CU scheduler favors MFMA-ready waves
// over the other block's staging/exp waves.
__global__ __launch_bounds__(1024, 4) void fused_part(
    const _Float16* __restrict__ x1t, const _Float16* __restrict__ x2t,
    const unsigned short* __restrict__ x1f, const unsigned short* __restrict__ x2f,
    float* __restrict__ accP1, float* __restrict__ cs1,
    float* __restrict__ accP2, float* __restrict__ cs2,
    int P, int passSel)
{
    __shared__ unsigned short AF[8192];   // 64 rows x 128 c fp16, swizzled 16B units
    __shared__ unsigned short PA[8192];   // 128 c x 64 rows bf16, swizzled
    __shared__ unsigned short EB[8192];   // 128 cols x 64 rows bf16, swizzled

    int bid = blockIdx.x;
    int pass, bidp;
    if (passSel < 0) { pass = bid >> 8; bidp = bid & 255; }
    else             { pass = passSel;  bidp = bid; }
    int xcd = bidp & 7, grp = bidp >> 3;  // grp 0..16P-1
    int b = xcd >> 1;                     // 2 XCDs per batch (L2 locality)
    int slice = (grp & 15) + 16 * (xcd & 1);   // 0..31 (128 cols each)
    int part = grp >> 4;                  // 0..P-1
    int tid = threadIdx.x;
    int wave = tid >> 6, lane = tid & 63;
    int l16 = lane & 15, lg = lane >> 4;
    int nt = wave & 3, mh = wave >> 2;    // gram: row-tile nt, col-32-group mh
    int swz = l16 & 7;
    int NC = 64 / P;
    int ch0 = part * NC, ch1 = ch0 + NC;

    const _Float16* loopT  = pass ? x2t : x1t;
    const _Float16* blockT = pass ? x1t : x2t;
    const unsigned short* loopF = pass ? x2f : x1f;
    float* accPo = pass ? accP2 : accP1;
    float* cso   = pass ? cs2   : cs1;

    const _Float16* lT = loopT + (size_t)b * HWSZ * CCH;
    const _Float16* bT = blockT + (size_t)b * HWSZ * CCH;
    const unsigned short* lF = loopF + (size_t)b * CCH * HWSZ;

    // hoist gram B frags: col = slice*128 + mh*32 + tt*16 + l16, K=128
    half8 bfrag[2][4];
    #pragma unroll
    for (int tt = 0; tt < 2; ++tt)
        #pragma unroll
        for (int ks = 0; ks < 4; ++ks)
            bfrag[tt][ks] = *(const half8*)&bT[
                (size_t)(slice * 128 + mh * 32 + tt * 16 + l16) * CCH + ks * 32 + lg * 8];

    // staging addressing: thread owns one 16B unit of each tile.
    int arow = tid >> 4, as_ = tid & 15;
    const _Float16* afsrc = lT + (size_t)arow * CCH + as_ * 8;
    int afw = (arow * 16 + (as_ ^ (arow & 7))) * 8;      // ushort index
    int pc = tid >> 3, ps = tid & 7;
    const unsigned short* pasrc = lF + (size_t)pc * HWSZ + ps * 8;
    int paw = (pc * 8 + (ps ^ (pc & 7))) * 8;            // ushort index

    float csum0 = 0.f, csum1 = 0.f;
    floatx4 accP[2][2];
    #pragma unroll
    for (int ci = 0; ci < 2; ++ci)
        #pragma unroll
        for (int cj = 0; cj < 2; ++cj) accP[ci][cj] = (floatx4){0.f, 0.f, 0.f, 0.f};

    // E-tile addresses (loop-invariant)
    int wo0 = (mh * 32 + l16) * 64 + (((nt * 2 + (lg >> 1)) ^ swz) << 3) + ((lg & 1) << 2);
    int wo1 = wo0 + 16 * 64;

    // prologue: stage chunk ch0
    {
        floatx4 ga = *(const floatx4*)(afsrc + (size_t)ch0 * 64 * CCH);
        floatx4 gp = *(const floatx4*)(pasrc + ch0 * 64);
        *(floatx4*)&AF[afw] = ga;
        *(floatx4*)&PA[paw] = gp;
    }
    __syncthreads();

    for (int t = ch0; t < ch1; ++t) {
        int t1 = (t + 1 < ch1) ? t + 1 : t;
        // issue next-chunk staging loads (ride over both barriers)
        floatx4 ga = *(const floatx4*)(afsrc + (size_t)t1 * 64 * CCH);
        floatx4 gp = *(const floatx4*)(pasrc + t1 * 64);
        // ---- gram: rows nt*16.., cols mh*32 + {0,16} + l16, K=128 (fp16)
        half8 afr[4];
        #pragma unroll
        for (int ks = 0; ks < 4; ++ks)
            afr[ks] = *(const half8*)&AF[((nt * 16 + l16) * 16 + ((ks * 4 + lg) ^ swz)) * 8];
        floatx4 accA0 = {0.f, 0.f, 0.f, 0.f}, accA1 = {0.f, 0.f, 0.f, 0.f};
        __builtin_amdgcn_s_setprio(1);   // T5: favor MFMA-ready waves
        #pragma unroll
        for (int ks = 0; ks < 4; ++ks) {
            accA0 = __builtin_amdgcn_mfma_f32_16x16x32_f16(afr[ks], bfrag[0][ks], accA0, 0, 0, 0);
            accA1 = __builtin_amdgcn_mfma_f32_16x16x32_f16(afr[ks], bfrag[1][ks], accA1, 0, 0, 0);
        }
        __builtin_amdgcn_s_setprio(0);
        // ---- exp (no max-sub: |A| << 88) + pk-bf16 pack + colsum partials
        float v00 = __expf(accA0[0]), v01 = __expf(accA0[1]);
        float v02 = __expf(accA0[2]), v03 = __expf(accA0[3]);
        float v10 = __expf(accA1[0]), v11 = __expf(accA1[1]);
        float v12 = __expf(accA1[2]), v13 = __expf(accA1[3]);
        csum0 += (v00 + v01) + (v02 + v03);
        csum1 += (v10 + v11) + (v12 + v13);
        uint2v e0 = (uint2v){cvtpk(v00, v01), cvtpk(v02, v03)};
        uint2v e1 = (uint2v){cvtpk(v10, v11), cvtpk(v12, v13)};
        *(uint2v*)&EB[wo0] = e0;
        *(uint2v*)&EB[wo1] = e1;
        FBAR();   // B1: E visible; all AF reads of tile t complete block-wide
        // ---- PV: accP[c-tiles nt*2+ci][col-tiles mh*2+cj], k = 64 rows (bf16)
        #pragma unroll
        for (int kf = 0; kf < 2; ++kf) {
            short8 paf[2], ebf[2];
            #pragma unroll
            for (int ci = 0; ci < 2; ++ci) {
                int c = (nt * 2 + ci) * 16 + l16;
                paf[ci] = *(const short8*)&PA[(c * 8 + ((kf * 4 + lg) ^ swz)) * 8];
            }
            #pragma unroll
            for (int cj = 0; cj < 2; ++cj) {
                int ecol = (mh * 2 + cj) * 16 + l16;
                ebf[cj] = *(const short8*)&EB[ecol * 64 + (((kf * 4 + lg) ^ swz) << 3)];
            }
            __builtin_amdgcn_s_setprio(1);   // T5
            #pragma unroll
            for (int ci = 0; ci < 2; ++ci)
                #pragma unroll
                for (int cj = 0; cj < 2; ++cj)
                    accP[ci][cj] = __builtin_amdgcn_mfma_f32_16x16x32_bf16(
                        paf[ci], ebf[cj], accP[ci][cj], 0, 0, 0);
            __builtin_amdgcn_s_setprio(0);
        }
        // ---- stage writes: AF (readers finished at B1), then barrier, then PA
        *(floatx4*)&AF[afw] = ga;
        FBAR();   // B2: PV reads of tile t complete; AF(t+1) visible
        *(floatx4*)&PA[paw] = gp;   // visible at next B1
    }
    __syncthreads();   // final PA write drained before aliasing

    // ---- colsum: deterministic cross-wave reduce (alias scratch onto EB)
    float* cspart = (float*)EB;   // [4][128]
    float v = csum0;
    v += __shfl_xor(v, 16, 64); v += __shfl_xor(v, 32, 64);
    float w = csum1;
    w += __shfl_xor(w, 16, 64); w += __shfl_xor(w, 32, 64);
    if (lane < 16) {
        cspart[nt * 128 + mh * 32 + lane] = v;
        cspart[nt * 128 + mh * 32 + 16 + lane] = w;
    }
    __syncthreads();
    size_t sbase = ((size_t)part * BATCH + b) * 32 + slice;
    if (tid < 128)
        cso[sbase * 128 + tid] = cspart[tid] + cspart[128 + tid] +
                                 cspart[256 + tid] + cspart[384 + tid];

    // ---- store partial accP: c = (nt*2+ci)*16 + lg*4 + rr, col = (mh*2+cj)*16 + l16
    float* po = accPo + sbase * (128 * 128);
    #pragma unroll
    for (int ci = 0; ci < 2; ++ci)
        #pragma unroll
        for (int cj = 0; cj < 2; ++cj)
            #pragma unroll
            for (int rr = 0; rr < 4; ++rr)
                po[(size_t)((nt * 2 + ci) * 16 + lg * 4 + rr) * 128 +
                   (mh * 2 + cj) * 16 + l16] = accP[ci][cj][rr];
}

// merged epilogue: one block per (b, 64-col strip); computes BOTH passes'
// contributions and writes out once.
__global__ __launch_bounds__(512) void combine2_kernel(
    const float* __restrict__ accP1, const float* __restrict__ cs1,
    const float* __restrict__ accP2, const float* __restrict__ cs2,
    const float* __restrict__ x1, const float* __restrict__ x2,
    const float* __restrict__ gw, const float* __restrict__ cwp,
    float* __restrict__ out, int P)
{
    __shared__ float red[512];
    __shared__ float gws[CCH];
    int b = blockIdx.x >> 6, s2 = blockIdx.x & 63;   // 64-col strip
    int tid = threadIdx.x;
    if (tid < CCH) gws[tid] = gw[tid];
    __syncthreads();
    int c64 = tid & 63, cg = tid >> 6;    // 8 c-groups x 16 c
    int slice = s2 >> 1;
    int colin = (s2 & 1) * 64 + c64;      // col within 128-col slice
    int colg  = s2 * 64 + c64;            // global col
    float d1 = 0.f, d2 = 0.f;
    for (int p = 0; p < P; ++p) {
        size_t sb = (((size_t)p * BATCH + b) * 32 + slice) * 128;
        d1 += cs1[sb + colin];
        d2 += cs2[sb + colin];
    }
    float inv1 = 1.f / d1, inv2 = 1.f / d2;
    float acc = 0.f;
    #pragma unroll 4
    for (int ci = 0; ci < 16; ++ci) {
        int c = cg * 16 + ci;
        size_t fo = (size_t)c * 128 + colin;
        float s1 = 0.f, s2v = 0.f;
        for (int p = 0; p < P; ++p) {
            size_t sb = ((((size_t)p * BATCH + b) * 32 + slice) * (size_t)128) * 128;
            s1  += accP1[sb + fo];
            s2v += accP2[sb + fo];
        }
        float a1 = s1 * inv1, a2 = s2v * inv2;
        float m1 = 1.f / (1.f + __expf(-a1));
        float m2 = 1.f / (1.f + __expf(-a2));
        size_t xei = ((size_t)b * CCH + c) * HWSZ + colg;
        acc += gws[c] * (m1 * x2[xei] + m2 * x1[xei]);
    }
    red[tid] = acc;
    __syncthreads();
    if (tid < 64) {
        float t = 0.f;
        #pragma unroll
        for (int g = 0; g < 8; ++g) t += red[tid + 64 * g];
        out[(size_t)b * HWSZ + s2 * 64 + tid] = cwp[0] * t;
    }
}

// single-pass combine (fallback when workspace can't hold both passes)
template<int ACCUM>
__global__ __launch_bounds__(256) void combine_kernel(
    const float* __restrict__ accPp, const float* __restrict__ csp,
    const float* __restrict__ xe, const float* __restrict__ gw,
    const float* __restrict__ cwp, float* __restrict__ out, int P)
{
    __shared__ float red[256];
    __shared__ float gws[CCH];
    int b = blockIdx.x >> 5, slice = blockIdx.x & 31;
    int tid = threadIdx.x;
    if (tid < CCH) gws[tid] = gw[tid];
    __syncthreads();
    int col = tid & 127, half = tid >> 7;
    float cs = 0.f;
    for (int p = 0; p < P; ++p)
        cs += csp[(((size_t)p * BATCH + b) * 32 + slice) * 128 + col];
    float inv = 1.f / cs;
    float acc = 0.f;
    for (int ci = 0; ci < 64; ++ci) {
        int c = half * 64 + ci;
        float s = 0.f;
        for (int p = 0; p < P; ++p)
            s += accPp[((((size_t)p * BATCH + b) * 32 + slice) * 128 + c) * 128 + col];
        float att = s * inv;
        float mask = 1.f / (1.f + __expf(-att));
        acc += gws[c] * mask * xe[((size_t)b * CCH + c) * HWSZ + slice * 128 + col];
    }
    red[tid] = acc;
    __syncthreads();
    if (tid < 128) {
        float vv = cwp[0] * (red[tid] + red[tid + 128]);
        size_t o = (size_t)b * HWSZ + slice * 128 + tid;
        if (ACCUM) out[o] += vv; else out[o] = vv;
    }
}

extern "C" void kernel_launch(void* const* d_in, const int* in_sizes, int n_in,
                              void* d_out, int out_size, void* d_ws, size_t ws_size,
                              hipStream_t stream) {
    const float* x1 = (const float*)d_in[0];
    const float* x2 = (const float*)d_in[1];
    const float* gw = (const float*)d_in[2];
    const float* cw = (const float*)d_in[3];
    float* out = (float*)d_out;

    char* ws = (char*)d_ws;
    size_t elems = (size_t)BATCH * CCH * HWSZ;  // 2M
    _Float16* x1t = (_Float16*)ws;
    _Float16* x2t = (_Float16*)(ws + elems * 2);
    unsigned short* x1f = (unsigned short*)(ws + elems * 4);
    unsigned short* x2f = (unsigned short*)(ws + elems * 6);
    char* pbase = ws + elems * 8;               // 16 MB used by prep arrays

    // partials per pass: accP P*B*32*128*128*4 + cs P*B*32*128*4
    auto region = [](int P) {
        return (size_t)P * BATCH * 32 * 128 * 128 * 4 +
               (size_t)P * BATCH * 32 * 128 * 4;
    };
    size_t avail = (ws_size > elems * 8) ? ws_size - elems * 8 : 0;
    int P; bool dual;
    if      (avail >= 2 * region(2)) { P = 2; dual = true;  }
    else if (avail >=     region(2)) { P = 2; dual = false; }
    else                             { P = 1; dual = false; }

    size_t accPbytes = (size_t)P * BATCH * 32 * 128 * 128 * 4;
    float* accP1 = (float*)pbase;
    float* cs1   = (float*)(pbase + accPbytes);
    float* accP2 = dual ? (float*)(pbase + region(P)) : accP1;
    float* cs2   = dual ? (float*)(pbase + region(P) + accPbytes) : cs1;

    prep_kernel<<<4096, 256, 0, stream>>>(x1, x2, x1t, x2t, x1f, x2f);

    if (dual) {
        // BOTH passes in one launch: 2 blocks/CU co-resident.
        fused_part<<<2 * 128 * P, 1024, 0, stream>>>(
            x1t, x2t, x1f, x2f, accP1, cs1, accP2, cs2, P, -1);
        combine2_kernel<<<BATCH * 64, 512, 0, stream>>>(
            accP1, cs1, accP2, cs2, x1, x2, gw, cw, out, P);
    } else {
        fused_part<<<128 * P, 1024, 0, stream>>>(
            x1t, x2t, x1f, x2f, accP1, cs1, accP1, cs1, P, 0);
        combine_kernel<0><<<BATCH * 32, 256, 0, stream>>>(accP1, cs1, x2, gw, cw, out, P);
        fused_part<<<128 * P, 1024, 0, stream>>>(
            x1t, x2t, x1f, x2f, accP1, cs1, accP1, cs1, P, 1);
        combine_kernel<1><<<BATCH * 32, 256, 0, stream>>>(accP1, cs1, x1, gw, cw, out, P);
    }
}